// Round 1
// baseline (1470.611 us; speedup 1.0000x reference)
//
#include <hip/hip_runtime.h>
#include <hip/hip_bf16.h>

#define IN_DIM 256
#define HC     64    // H*C for layer 1
#define OUT_DIM 40
#define NEG    0.2f

// ---------------- float atomic max via int/uint punning ----------------
__device__ inline void atomicMaxF32(float* addr, float val) {
  int bits = __float_as_int(val);
  if (bits >= 0) {
    atomicMax((int*)addr, bits);
  } else {
    atomicMin((unsigned int*)addr, (unsigned int)bits);
  }
}

__device__ inline float lrelu(float v) { return v > 0.f ? v : NEG * v; }

// ---------------- init: zeros + (-inf) fills ----------------
__global__ void init_kernel(float* __restrict__ m1, float* __restrict__ z1,
                            float* __restrict__ agg1, float* __restrict__ m2,
                            float* __restrict__ z2, float* __restrict__ out, int n) {
  int i = blockIdx.x * blockDim.x + threadIdx.x;
  int total = n * 64;
  if (i >= total) return;
  agg1[i] = 0.f;
  if (i < n * 4)  { m1[i] = -INFINITY; z1[i] = 0.f; }
  if (i < n)      { m2[i] = -INFINITY; z2[i] = 0.f; }
  if (i < n * 40) out[i] = 0.f;
}

// ---------------- layer 1 projection: xp1 = x @ W1, es1/ed1 dots ----------------
// 16 rows per block, 256 threads = 4 waves; wave w owns rows [16b+4w, 16b+4w+4),
// thread col = lane. W1 staged in LDS in two K-halves (32KB), x rows in LDS (16KB).
__global__ __launch_bounds__(256) void gemm1_kernel(
    const float* __restrict__ x, const float* __restrict__ W1,
    const float* __restrict__ a_s, const float* __restrict__ a_d,
    float* __restrict__ xp1, float* __restrict__ es1, float* __restrict__ ed1, int n) {
  __shared__ float Wl[128 * HC];       // 32 KB (half of W1)
  __shared__ float xl[16][IN_DIM];     // 16 KB
  int tid = threadIdx.x;
  int row0 = blockIdx.x * 16;

  for (int i = tid; i < 16 * IN_DIM; i += 256) {
    int r = i >> 8, k = i & 255;
    int row = row0 + r;
    xl[r][k] = (row < n) ? x[(size_t)row * IN_DIM + k] : 0.f;
  }

  int wave = tid >> 6, col = tid & 63;
  int rbase = wave * 4;
  float acc[4] = {0.f, 0.f, 0.f, 0.f};

  for (int ph = 0; ph < 2; ++ph) {
    for (int i = tid; i < 128 * HC; i += 256) Wl[i] = W1[ph * 128 * HC + i];
    __syncthreads();
    #pragma unroll 4
    for (int k = 0; k < 128; ++k) {
      float w = Wl[k * HC + col];
      int kk = ph * 128 + k;
      #pragma unroll
      for (int r = 0; r < 4; ++r) acc[r] += xl[rbase + r][kk] * w;
    }
    __syncthreads();
  }

  #pragma unroll
  for (int r = 0; r < 4; ++r) {
    int row = row0 + rbase + r;          // uniform across the wave
    bool ok = row < n;
    float sum = acc[r];
    float ps = sum * a_s[col], pd = sum * a_d[col];
    #pragma unroll
    for (int o = 8; o; o >>= 1) {
      ps += __shfl_down(ps, o, 16);
      pd += __shfl_down(pd, o, 16);
    }
    if (ok) {
      xp1[(size_t)row * HC + col] = sum;
      if ((col & 15) == 0) {
        int h = col >> 4;
        es1[row * 4 + h] = ps;
        ed1[row * 4 + h] = pd;
      }
    }
  }
}

// ---------------- edge helpers ----------------
__device__ inline void edge_nodes(const int* __restrict__ ei, int E, int e, int& s, int& d) {
  if (e < E) { s = ei[e]; d = ei[E + e]; }
  else       { s = e - E; d = e - E; }     // self-loops appended
}

// ---------------- layer 1 edge pass A: segment max ----------------
__global__ void edge_max1_kernel(const int* __restrict__ ei,
                                 const float* __restrict__ es1, const float* __restrict__ ed1,
                                 float* __restrict__ m1, int E, int ET) {
  int e = blockIdx.x * blockDim.x + threadIdx.x;
  if (e >= ET) return;
  int s, d; edge_nodes(ei, E, e, s, d);
  #pragma unroll
  for (int h = 0; h < 4; ++h) {
    float v = lrelu(es1[s * 4 + h] + ed1[d * 4 + h]);
    atomicMaxF32(&m1[d * 4 + h], v);
  }
}

// ---------------- layer 1 edge pass B: exp-sum + weighted aggregate ----------------
// 16 lanes per edge: lane c handles channel c of each of the 4 heads -> coalesced atomics.
__global__ void edge_agg1_kernel(const int* __restrict__ ei,
                                 const float* __restrict__ es1, const float* __restrict__ ed1,
                                 const float* __restrict__ m1, const float* __restrict__ xp1,
                                 float* __restrict__ z1, float* __restrict__ agg1,
                                 int E, int ET) {
  int gid = blockIdx.x * blockDim.x + threadIdx.x;
  int e = gid >> 4, lane = gid & 15;
  if (e >= ET) return;
  int s, d; edge_nodes(ei, E, e, s, d);
  float ex[4];
  #pragma unroll
  for (int h = 0; h < 4; ++h) {
    float v = lrelu(es1[s * 4 + h] + ed1[d * 4 + h]);
    ex[h] = __expf(v - m1[d * 4 + h]);
  }
  if (lane < 4) atomicAdd(&z1[d * 4 + lane], ex[lane]);
  #pragma unroll
  for (int h = 0; h < 4; ++h) {
    atomicAdd(&agg1[(size_t)d * HC + h * 16 + lane],
              xp1[(size_t)s * HC + h * 16 + lane] * ex[h]);
  }
}

// ---------------- finalize layer 1 + layer 2 projection ----------------
// 4 rows per block (1 wave each). h = relu(agg1/z1 + b1); xp2 = h @ W2; es2/ed2 dots.
__global__ __launch_bounds__(256) void layer2_kernel(
    const float* __restrict__ agg1, const float* __restrict__ z1, const float* __restrict__ b1,
    const float* __restrict__ W2, const float* __restrict__ a_s2, const float* __restrict__ a_d2,
    float* __restrict__ xp2, float* __restrict__ es2, float* __restrict__ ed2, int n) {
  __shared__ float W2l[64 * OUT_DIM];  // 10.25 KB
  __shared__ float hl[4][64];
  int tid = threadIdx.x;
  for (int i = tid; i < 64 * OUT_DIM; i += 256) W2l[i] = W2[i];
  int r = tid >> 6, j = tid & 63;
  int row = blockIdx.x * 4 + r;
  if (row < n) {
    float v = agg1[(size_t)row * 64 + j];
    float z = z1[row * 4 + (j >> 4)];
    v = v / (z + 1e-16f) + b1[j];
    hl[r][j] = fmaxf(v, 0.f);
  }
  __syncthreads();
  if (row >= n) return;
  float ps = 0.f, pd = 0.f;
  if (j < OUT_DIM) {
    float sum = 0.f;
    #pragma unroll 8
    for (int k = 0; k < 64; ++k) sum += hl[r][k] * W2l[k * OUT_DIM + j];
    xp2[(size_t)row * OUT_DIM + j] = sum;
    ps = sum * a_s2[j];
    pd = sum * a_d2[j];
  }
  #pragma unroll
  for (int o = 32; o; o >>= 1) {
    ps += __shfl_down(ps, o, 64);
    pd += __shfl_down(pd, o, 64);
  }
  if (j == 0) { es2[row] = ps; ed2[row] = pd; }
}

// ---------------- layer 2 edge pass A ----------------
__global__ void edge_max2_kernel(const int* __restrict__ ei,
                                 const float* __restrict__ es2, const float* __restrict__ ed2,
                                 float* __restrict__ m2, int E, int ET) {
  int e = blockIdx.x * blockDim.x + threadIdx.x;
  if (e >= ET) return;
  int s, d; edge_nodes(ei, E, e, s, d);
  float v = lrelu(es2[s] + ed2[d]);
  atomicMaxF32(&m2[d], v);
}

// ---------------- layer 2 edge pass B: aggregate into d_out ----------------
// 8 lanes per edge, each lane handles 5 channels (lane + 8k) -> coalesced atomics.
__global__ void edge_agg2_kernel(const int* __restrict__ ei,
                                 const float* __restrict__ es2, const float* __restrict__ ed2,
                                 const float* __restrict__ m2, const float* __restrict__ xp2,
                                 float* __restrict__ z2, float* __restrict__ out,
                                 int E, int ET) {
  int gid = blockIdx.x * blockDim.x + threadIdx.x;
  int e = gid >> 3, lane = gid & 7;
  if (e >= ET) return;
  int s, d; edge_nodes(ei, E, e, s, d);
  float v = lrelu(es2[s] + ed2[d]);
  float ex = __expf(v - m2[d]);
  if (lane == 0) atomicAdd(&z2[d], ex);
  #pragma unroll
  for (int k = 0; k < 5; ++k) {
    int c = lane + 8 * k;
    atomicAdd(&out[(size_t)d * OUT_DIM + c], xp2[(size_t)s * OUT_DIM + c] * ex);
  }
}

// ---------------- final normalize + bias ----------------
__global__ void final_kernel(float* __restrict__ out, const float* __restrict__ z2,
                             const float* __restrict__ b2, int n) {
  int i = blockIdx.x * blockDim.x + threadIdx.x;
  if (i >= n * OUT_DIM) return;
  int node = i / OUT_DIM, c = i - node * OUT_DIM;
  out[i] = out[i] / (z2[node] + 1e-16f) + b2[c];
}

extern "C" void kernel_launch(void* const* d_in, const int* in_sizes, int n_in,
                              void* d_out, int out_size, void* d_ws, size_t ws_size,
                              hipStream_t stream) {
  const float* x    = (const float*)d_in[0];
  const int*   ei   = (const int*)d_in[1];
  const float* W1   = (const float*)d_in[2];
  const float* a_s1 = (const float*)d_in[3];
  const float* a_d1 = (const float*)d_in[4];
  const float* b1   = (const float*)d_in[5];
  const float* W2   = (const float*)d_in[6];
  const float* a_s2 = (const float*)d_in[7];
  const float* a_d2 = (const float*)d_in[8];
  const float* b2   = (const float*)d_in[9];

  int n  = in_sizes[0] / IN_DIM;
  int E  = in_sizes[1] / 2;
  int ET = E + n;
  float* out = (float*)d_out;

  float* ws = (float*)d_ws;
  size_t off = 0;
  auto alloc = [&](size_t elems) -> float* {
    float* p = ws + off;
    off += (elems + 63) & ~(size_t)63;
    return p;
  };
  float* xp1  = alloc((size_t)n * 64);
  float* es1  = alloc((size_t)n * 4);
  float* ed1  = alloc((size_t)n * 4);
  float* m1   = alloc((size_t)n * 4);
  float* z1   = alloc((size_t)n * 4);
  float* agg1 = alloc((size_t)n * 64);
  float* xp2  = alloc((size_t)n * OUT_DIM);
  float* es2  = alloc((size_t)n);
  float* ed2  = alloc((size_t)n);
  float* m2   = alloc((size_t)n);
  float* z2   = alloc((size_t)n);

  init_kernel<<<(n * 64 + 255) / 256, 256, 0, stream>>>(m1, z1, agg1, m2, z2, out, n);
  gemm1_kernel<<<(n + 15) / 16, 256, 0, stream>>>(x, W1, a_s1, a_d1, xp1, es1, ed1, n);
  edge_max1_kernel<<<(ET + 255) / 256, 256, 0, stream>>>(ei, es1, ed1, m1, E, ET);
  edge_agg1_kernel<<<(int)(((size_t)ET * 16 + 255) / 256), 256, 0, stream>>>(
      ei, es1, ed1, m1, xp1, z1, agg1, E, ET);
  layer2_kernel<<<(n + 3) / 4, 256, 0, stream>>>(agg1, z1, b1, W2, a_s2, a_d2, xp2, es2, ed2, n);
  edge_max2_kernel<<<(ET + 255) / 256, 256, 0, stream>>>(ei, es2, ed2, m2, E, ET);
  edge_agg2_kernel<<<(int)(((size_t)ET * 8 + 255) / 256), 256, 0, stream>>>(
      ei, es2, ed2, m2, xp2, z2, out, E, ET);
  final_kernel<<<(n * OUT_DIM + 255) / 256, 256, 0, stream>>>(out, z2, b2, n);
}

// Round 2
// 724.573 us; speedup vs baseline: 2.0296x; 2.0296x over previous
//
#include <hip/hip_runtime.h>
#include <hip/hip_bf16.h>

#define IN_DIM 256
#define HC     64    // H*C for layer 1
#define OUT_DIM 40
#define NEG    0.2f

__device__ inline float lrelu(float v) { return v > 0.f ? v : NEG * v; }

// ---------------- zero deg/cnt ----------------
__global__ void zero_kernel(int* __restrict__ deg, int* __restrict__ cnt, int n) {
  int i = blockIdx.x * blockDim.x + threadIdx.x;
  if (i < n) { deg[i] = 0; cnt[i] = 0; }
}

// ---------------- CSR build: histogram ----------------
__global__ void count_kernel(const int* __restrict__ ei, int* __restrict__ deg,
                             int E, int ET) {
  int e = blockIdx.x * blockDim.x + threadIdx.x;
  if (e >= ET) return;
  int d = (e < E) ? ei[E + e] : (e - E);   // self-loops appended
  atomicAdd(&deg[d], 1);
}

// ---------------- CSR build: 3-phase exclusive scan (1024 elems/block) ----------------
__global__ void scan1_kernel(const int* __restrict__ deg, int* __restrict__ offs,
                             int* __restrict__ partial, int n) {
  __shared__ int sm[256];
  int tid = threadIdx.x;
  int base = blockIdx.x * 1024 + tid * 4;
  int v0 = 0, v1 = 0, v2 = 0, v3 = 0;
  if (base + 0 < n) v0 = deg[base + 0];
  if (base + 1 < n) v1 = deg[base + 1];
  if (base + 2 < n) v2 = deg[base + 2];
  if (base + 3 < n) v3 = deg[base + 3];
  int t = v0 + v1 + v2 + v3;
  sm[tid] = t; __syncthreads();
  for (int o = 1; o < 256; o <<= 1) {
    int x = (tid >= o) ? sm[tid - o] : 0;
    __syncthreads();
    sm[tid] += x;
    __syncthreads();
  }
  int excl = sm[tid] - t;
  if (base + 0 < n) offs[base + 0] = excl;
  if (base + 1 < n) offs[base + 1] = excl + v0;
  if (base + 2 < n) offs[base + 2] = excl + v0 + v1;
  if (base + 3 < n) offs[base + 3] = excl + v0 + v1 + v2;
  if (tid == 255) partial[blockIdx.x] = sm[255];
}

__global__ void scan2_kernel(int* __restrict__ partial, int nb) {
  __shared__ int sm[256];
  int tid = threadIdx.x;
  int base = 0;
  for (int c = 0; c < nb; c += 256) {
    int idx = c + tid;
    int t = (idx < nb) ? partial[idx] : 0;
    sm[tid] = t; __syncthreads();
    for (int o = 1; o < 256; o <<= 1) {
      int x = (tid >= o) ? sm[tid - o] : 0;
      __syncthreads();
      sm[tid] += x;
      __syncthreads();
    }
    if (idx < nb) partial[idx] = base + sm[tid] - t;
    base += sm[255];
    __syncthreads();
  }
}

__global__ void scan3_kernel(int* __restrict__ offs, const int* __restrict__ partial,
                             int n, int ET) {
  int i = blockIdx.x * blockDim.x + threadIdx.x;
  if (i < n) offs[i] += partial[i >> 10];
  if (i == 0) offs[n] = ET;
}

// ---------------- CSR build: scatter src ids into dst-sorted order ----------------
__global__ void scatter_kernel(const int* __restrict__ ei, const int* __restrict__ offs,
                               int* __restrict__ cnt, int* __restrict__ srcs,
                               int E, int ET) {
  int e = blockIdx.x * blockDim.x + threadIdx.x;
  if (e >= ET) return;
  int s, d;
  if (e < E) { s = ei[e]; d = ei[E + e]; }
  else       { s = e - E; d = e - E; }
  int pos = offs[d] + atomicAdd(&cnt[d], 1);
  srcs[pos] = s;
}

// ---------------- layer 1 projection: xp1 = x @ W1, es1/ed1 dots ----------------
__global__ __launch_bounds__(256) void gemm1_kernel(
    const float* __restrict__ x, const float* __restrict__ W1,
    const float* __restrict__ a_s, const float* __restrict__ a_d,
    float* __restrict__ xp1, float* __restrict__ es1, float* __restrict__ ed1, int n) {
  __shared__ float Wl[128 * HC];       // 32 KB (half of W1)
  __shared__ float xl[16][IN_DIM];     // 16 KB
  int tid = threadIdx.x;
  int row0 = blockIdx.x * 16;

  for (int i = tid; i < 16 * IN_DIM; i += 256) {
    int r = i >> 8, k = i & 255;
    int row = row0 + r;
    xl[r][k] = (row < n) ? x[(size_t)row * IN_DIM + k] : 0.f;
  }

  int wave = tid >> 6, col = tid & 63;
  int rbase = wave * 4;
  float acc[4] = {0.f, 0.f, 0.f, 0.f};

  for (int ph = 0; ph < 2; ++ph) {
    for (int i = tid; i < 128 * HC; i += 256) Wl[i] = W1[ph * 128 * HC + i];
    __syncthreads();
    #pragma unroll 4
    for (int k = 0; k < 128; ++k) {
      float w = Wl[k * HC + col];
      int kk = ph * 128 + k;
      #pragma unroll
      for (int r = 0; r < 4; ++r) acc[r] += xl[rbase + r][kk] * w;
    }
    __syncthreads();
  }

  #pragma unroll
  for (int r = 0; r < 4; ++r) {
    int row = row0 + rbase + r;
    bool ok = row < n;
    float sum = acc[r];
    float ps = sum * a_s[col], pd = sum * a_d[col];
    #pragma unroll
    for (int o = 8; o; o >>= 1) {
      ps += __shfl_down(ps, o, 16);
      pd += __shfl_down(pd, o, 16);
    }
    if (ok) {
      xp1[(size_t)row * HC + col] = sum;
      if ((col & 15) == 0) {
        int h = col >> 4;
        es1[row * 4 + h] = ps;
        ed1[row * 4 + h] = pd;
      }
    }
  }
}

// ---------------- layer 1 aggregation: one wave per dst node, online softmax ----------------
__global__ __launch_bounds__(256) void agg1_csr(
    const int* __restrict__ offs, const int* __restrict__ srcs,
    const float* __restrict__ es1, const float* __restrict__ ed1,
    const float* __restrict__ xp1, const float* __restrict__ b1,
    float* __restrict__ h, int n) {
  int wid = (blockIdx.x * 256 + threadIdx.x) >> 6;
  if (wid >= n) return;
  int lane = threadIdx.x & 63, hd = lane >> 4;
  int beg = offs[wid], end = offs[wid + 1];   // deg >= 1 (self-loop)
  float edh = ed1[wid * 4 + hd];
  float m = -INFINITY, z = 0.f, acc = 0.f;
  int s = srcs[beg];
  float esv = es1[s * 4 + hd];
  float xv = xp1[(size_t)s * HC + lane];
  for (int e = beg; e < end; ) {
    int e2 = e + 1;
    float esv2 = 0.f, xv2 = 0.f;
    if (e2 < end) {
      int s2 = srcs[e2];
      esv2 = es1[s2 * 4 + hd];
      xv2 = xp1[(size_t)s2 * HC + lane];
    }
    float v = lrelu(esv + edh);
    float mn = fmaxf(m, v);
    float sc = __expf(m - mn);   // first iter: exp(-inf)=0
    float w = __expf(v - mn);
    z = z * sc + w;
    acc = acc * sc + w * xv;
    m = mn;
    e = e2; esv = esv2; xv = xv2;
  }
  h[(size_t)wid * HC + lane] = fmaxf(acc / (z + 1e-16f) + b1[lane], 0.f);
}

// ---------------- layer 2 projection: xp2 = h @ W2, es2/ed2 dots ----------------
__global__ __launch_bounds__(256) void layer2_kernel(
    const float* __restrict__ h, const float* __restrict__ W2,
    const float* __restrict__ a_s2, const float* __restrict__ a_d2,
    float* __restrict__ xp2, float* __restrict__ es2, float* __restrict__ ed2, int n) {
  __shared__ float W2l[64 * OUT_DIM];
  __shared__ float hl[4][64];
  int tid = threadIdx.x;
  for (int i = tid; i < 64 * OUT_DIM; i += 256) W2l[i] = W2[i];
  int r = tid >> 6, j = tid & 63;
  int row = blockIdx.x * 4 + r;
  if (row < n) hl[r][j] = h[(size_t)row * 64 + j];
  __syncthreads();
  if (row >= n) return;
  float ps = 0.f, pd = 0.f;
  if (j < OUT_DIM) {
    float sum = 0.f;
    #pragma unroll 8
    for (int k = 0; k < 64; ++k) sum += hl[r][k] * W2l[k * OUT_DIM + j];
    xp2[(size_t)row * OUT_DIM + j] = sum;
    ps = sum * a_s2[j];
    pd = sum * a_d2[j];
  }
  #pragma unroll
  for (int o = 32; o; o >>= 1) {
    ps += __shfl_down(ps, o, 64);
    pd += __shfl_down(pd, o, 64);
  }
  if (j == 0) { es2[row] = ps; ed2[row] = pd; }
}

// ---------------- layer 2 aggregation: one wave per dst node, writes d_out ----------------
__global__ __launch_bounds__(256) void agg2_csr(
    const int* __restrict__ offs, const int* __restrict__ srcs,
    const float* __restrict__ es2, const float* __restrict__ ed2,
    const float* __restrict__ xp2, const float* __restrict__ b2,
    float* __restrict__ out, int n) {
  int wid = (blockIdx.x * 256 + threadIdx.x) >> 6;
  if (wid >= n) return;
  int lane = threadIdx.x & 63;
  int beg = offs[wid], end = offs[wid + 1];
  float edv = ed2[wid];
  float m = -INFINITY, z = 0.f, acc = 0.f;
  int s = srcs[beg];
  float esv = es2[s];
  float xv = (lane < OUT_DIM) ? xp2[(size_t)s * OUT_DIM + lane] : 0.f;
  for (int e = beg; e < end; ) {
    int e2 = e + 1;
    float esv2 = 0.f, xv2 = 0.f;
    if (e2 < end) {
      int s2 = srcs[e2];
      esv2 = es2[s2];
      xv2 = (lane < OUT_DIM) ? xp2[(size_t)s2 * OUT_DIM + lane] : 0.f;
    }
    float v = lrelu(esv + edv);
    float mn = fmaxf(m, v);
    float sc = __expf(m - mn);
    float w = __expf(v - mn);
    z = z * sc + w;
    acc = acc * sc + w * xv;
    m = mn;
    e = e2; esv = esv2; xv = xv2;
  }
  if (lane < OUT_DIM)
    out[(size_t)wid * OUT_DIM + lane] = acc / (z + 1e-16f) + b2[lane];
}

extern "C" void kernel_launch(void* const* d_in, const int* in_sizes, int n_in,
                              void* d_out, int out_size, void* d_ws, size_t ws_size,
                              hipStream_t stream) {
  const float* x    = (const float*)d_in[0];
  const int*   ei   = (const int*)d_in[1];
  const float* W1   = (const float*)d_in[2];
  const float* a_s1 = (const float*)d_in[3];
  const float* a_d1 = (const float*)d_in[4];
  const float* b1   = (const float*)d_in[5];
  const float* W2   = (const float*)d_in[6];
  const float* a_s2 = (const float*)d_in[7];
  const float* a_d2 = (const float*)d_in[8];
  const float* b2   = (const float*)d_in[9];

  int n  = in_sizes[0] / IN_DIM;
  int E  = in_sizes[1] / 2;
  int ET = E + n;
  float* out = (float*)d_out;

  char* ws = (char*)d_ws;
  size_t off = 0;
  auto alloc = [&](size_t bytes) -> void* {
    void* p = ws + off;
    off = (off + bytes + 255) & ~(size_t)255;
    return p;
  };
  float* xp1   = (float*)alloc((size_t)n * HC * 4);      // reused as xp2 later
  float* h     = (float*)alloc((size_t)n * HC * 4);
  float* es1   = (float*)alloc((size_t)n * 4 * 4);
  float* ed1   = (float*)alloc((size_t)n * 4 * 4);
  float* es2   = (float*)alloc((size_t)n * 4);
  float* ed2   = (float*)alloc((size_t)n * 4);
  int*   deg   = (int*)alloc((size_t)n * 4);
  int*   cnt   = (int*)alloc((size_t)n * 4);
  int*   offs  = (int*)alloc((size_t)(n + 1) * 4);
  int*   part  = (int*)alloc((size_t)1024 * 4);
  int*   srcs  = (int*)alloc((size_t)ET * 4);
  float* xp2   = xp1;  // xp1 dead after agg1_csr

  int nb = (n + 1023) / 1024;   // scan blocks

  zero_kernel<<<(n + 255) / 256, 256, 0, stream>>>(deg, cnt, n);
  count_kernel<<<(ET + 255) / 256, 256, 0, stream>>>(ei, deg, E, ET);
  scan1_kernel<<<nb, 256, 0, stream>>>(deg, offs, part, n);
  scan2_kernel<<<1, 256, 0, stream>>>(part, nb);
  scan3_kernel<<<(n + 255) / 256, 256, 0, stream>>>(offs, part, n, ET);
  scatter_kernel<<<(ET + 255) / 256, 256, 0, stream>>>(ei, offs, cnt, srcs, E, ET);

  gemm1_kernel<<<(n + 15) / 16, 256, 0, stream>>>(x, W1, a_s1, a_d1, xp1, es1, ed1, n);
  agg1_csr<<<(n * 64 + 255) / 256, 256, 0, stream>>>(offs, srcs, es1, ed1, xp1, b1, h, n);
  layer2_kernel<<<(n + 3) / 4, 256, 0, stream>>>(h, W2, a_s2, a_d2, xp2, es2, ed2, n);
  agg2_csr<<<(n * 64 + 255) / 256, 256, 0, stream>>>(offs, srcs, es2, ed2, xp2, b2, out, n);
}

// Round 3
// 676.559 us; speedup vs baseline: 2.1737x; 1.0710x over previous
//
#include <hip/hip_runtime.h>
#include <hip/hip_bf16.h>

#define IN_DIM 256
#define HC     64    // H*C for layer 1
#define OUT_DIM 40
#define NEG    0.2f

typedef __bf16 bf16x8 __attribute__((ext_vector_type(8)));
typedef float  f32x4  __attribute__((ext_vector_type(4)));

__device__ inline float lrelu(float v) { return v > 0.f ? v : NEG * v; }

// ---------------- zero deg/cnt ----------------
__global__ void zero_kernel(int* __restrict__ deg, int* __restrict__ cnt, int n) {
  int i = blockIdx.x * blockDim.x + threadIdx.x;
  if (i < n) { deg[i] = 0; cnt[i] = 0; }
}

// ---------------- CSR build: histogram ----------------
__global__ void count_kernel(const int* __restrict__ ei, int* __restrict__ deg,
                             int E, int ET) {
  int e = blockIdx.x * blockDim.x + threadIdx.x;
  if (e >= ET) return;
  int d = (e < E) ? ei[E + e] : (e - E);   // self-loops appended
  atomicAdd(&deg[d], 1);
}

// ---------------- CSR build: 3-phase exclusive scan (1024 elems/block) ----------------
__global__ void scan1_kernel(const int* __restrict__ deg, int* __restrict__ offs,
                             int* __restrict__ partial, int n) {
  __shared__ int sm[256];
  int tid = threadIdx.x;
  int base = blockIdx.x * 1024 + tid * 4;
  int v0 = 0, v1 = 0, v2 = 0, v3 = 0;
  if (base + 0 < n) v0 = deg[base + 0];
  if (base + 1 < n) v1 = deg[base + 1];
  if (base + 2 < n) v2 = deg[base + 2];
  if (base + 3 < n) v3 = deg[base + 3];
  int t = v0 + v1 + v2 + v3;
  sm[tid] = t; __syncthreads();
  for (int o = 1; o < 256; o <<= 1) {
    int x = (tid >= o) ? sm[tid - o] : 0;
    __syncthreads();
    sm[tid] += x;
    __syncthreads();
  }
  int excl = sm[tid] - t;
  if (base + 0 < n) offs[base + 0] = excl;
  if (base + 1 < n) offs[base + 1] = excl + v0;
  if (base + 2 < n) offs[base + 2] = excl + v0 + v1;
  if (base + 3 < n) offs[base + 3] = excl + v0 + v1 + v2;
  if (tid == 255) partial[blockIdx.x] = sm[255];
}

__global__ void scan2_kernel(int* __restrict__ partial, int nb) {
  __shared__ int sm[256];
  int tid = threadIdx.x;
  int base = 0;
  for (int c = 0; c < nb; c += 256) {
    int idx = c + tid;
    int t = (idx < nb) ? partial[idx] : 0;
    sm[tid] = t; __syncthreads();
    for (int o = 1; o < 256; o <<= 1) {
      int x = (tid >= o) ? sm[tid - o] : 0;
      __syncthreads();
      sm[tid] += x;
      __syncthreads();
    }
    if (idx < nb) partial[idx] = base + sm[tid] - t;
    base += sm[255];
    __syncthreads();
  }
}

__global__ void scan3_kernel(int* __restrict__ offs, const int* __restrict__ partial,
                             int n, int ET) {
  int i = blockIdx.x * blockDim.x + threadIdx.x;
  if (i < n) offs[i] += partial[i >> 10];
  if (i == 0) offs[n] = ET;
}

// ---------------- CSR build: scatter src ids into dst-sorted order ----------------
__global__ void scatter_kernel(const int* __restrict__ ei, const int* __restrict__ offs,
                               int* __restrict__ cnt, int* __restrict__ srcs,
                               int E, int ET) {
  int e = blockIdx.x * blockDim.x + threadIdx.x;
  if (e >= ET) return;
  int s, d;
  if (e < E) { s = ei[e]; d = ei[E + e]; }
  else       { s = e - E; d = e - E; }
  int pos = offs[d] + atomicAdd(&cnt[d], 1);
  srcs[pos] = s;
}

// ---------------- W1 prep: transpose to [64][256] and split into bf16 hi/lo ----------------
__global__ void wprep_kernel(const float* __restrict__ W1,
                             __bf16* __restrict__ Wt_hi, __bf16* __restrict__ Wt_lo) {
  int i = blockIdx.x * blockDim.x + threadIdx.x;   // over 256*64
  if (i >= IN_DIM * HC) return;
  int k = i >> 6, nn = i & 63;
  float f = W1[i];
  __bf16 h = (__bf16)f;
  __bf16 l = (__bf16)(f - (float)h);
  Wt_hi[nn * IN_DIM + k] = h;
  Wt_lo[nn * IN_DIM + k] = l;
}

// ---------------- layer 1 projection via MFMA (split-bf16, 3 products) ----------------
// Block = 4 waves; wave w computes rows [64*blk + 16w, +16) x all 64 cols.
// A frag: lane l -> row l&15, k = chunk*32 + (l>>4)*8 + {0..7}.
// B frag: lane l -> col (l&15)+16t, same k window (from transposed Wt).
// C frag: lane l -> col l&15, row (l>>4)*4 + reg.
__global__ __launch_bounds__(256) void gemm1_mfma(
    const float* __restrict__ x,
    const __bf16* __restrict__ Wt_hi, const __bf16* __restrict__ Wt_lo,
    const float* __restrict__ a_s, const float* __restrict__ a_d,
    float* __restrict__ xp1, float* __restrict__ es1, float* __restrict__ ed1, int n) {
  int wave = threadIdx.x >> 6, lane = threadIdx.x & 63;
  int l15 = lane & 15, kgrp = lane >> 4;
  int rowA = blockIdx.x * 64 + wave * 16 + l15;
  bool okA = rowA < n;
  const float* xrow = x + (size_t)rowA * IN_DIM;

  f32x4 acc[4] = {};
  #pragma unroll
  for (int c = 0; c < 8; ++c) {
    int k0 = c * 32 + kgrp * 8;
    f32x4 v0 = {}, v1 = {};
    if (okA) {
      v0 = *(const f32x4*)(xrow + k0);
      v1 = *(const f32x4*)(xrow + k0 + 4);
    }
    bf16x8 ahi, alo;
    #pragma unroll
    for (int i = 0; i < 4; ++i) {
      float f0 = v0[i], f1 = v1[i];
      __bf16 h0 = (__bf16)f0, h1 = (__bf16)f1;
      ahi[i]     = h0;
      ahi[4 + i] = h1;
      alo[i]     = (__bf16)(f0 - (float)h0);
      alo[4 + i] = (__bf16)(f1 - (float)h1);
    }
    #pragma unroll
    for (int t = 0; t < 4; ++t) {
      const __bf16* wph = Wt_hi + ((t * 16 + l15) * IN_DIM + k0);
      const __bf16* wpl = Wt_lo + ((t * 16 + l15) * IN_DIM + k0);
      bf16x8 bhi = *(const bf16x8*)wph;
      bf16x8 blo = *(const bf16x8*)wpl;
      acc[t] = __builtin_amdgcn_mfma_f32_16x16x32_bf16(ahi, bhi, acc[t], 0, 0, 0);
      acc[t] = __builtin_amdgcn_mfma_f32_16x16x32_bf16(ahi, blo, acc[t], 0, 0, 0);
      acc[t] = __builtin_amdgcn_mfma_f32_16x16x32_bf16(alo, bhi, acc[t], 0, 0, 0);
    }
  }

  // epilogue: write xp1 + fused es/ed attention dots (per-head = per 16-col tile)
  int rowbase = blockIdx.x * 64 + wave * 16 + kgrp * 4;
  #pragma unroll
  for (int t = 0; t < 4; ++t) {
    float as_v = a_s[t * 16 + l15], ad_v = a_d[t * 16 + l15];
    #pragma unroll
    for (int r = 0; r < 4; ++r) {
      int row = rowbase + r;
      float v = acc[t][r];
      bool ok = row < n;
      if (ok) xp1[(size_t)row * HC + t * 16 + l15] = v;
      float ps = v * as_v, pd = v * ad_v;
      #pragma unroll
      for (int o = 1; o < 16; o <<= 1) {
        ps += __shfl_xor(ps, o, 16);
        pd += __shfl_xor(pd, o, 16);
      }
      if (ok && l15 == 0) {
        es1[row * 4 + t] = ps;
        ed1[row * 4 + t] = pd;
      }
    }
  }
}

// ---------------- layer 1 aggregation: one wave per dst node, online softmax ----------------
__global__ __launch_bounds__(256) void agg1_csr(
    const int* __restrict__ offs, const int* __restrict__ srcs,
    const float* __restrict__ es1, const float* __restrict__ ed1,
    const float* __restrict__ xp1, const float* __restrict__ b1,
    float* __restrict__ h, int n) {
  int wid = (blockIdx.x * 256 + threadIdx.x) >> 6;
  if (wid >= n) return;
  int lane = threadIdx.x & 63, hd = lane >> 4;
  int beg = offs[wid], end = offs[wid + 1];   // deg >= 1 (self-loop)
  float edh = ed1[wid * 4 + hd];
  float m = -INFINITY, z = 0.f, acc = 0.f;
  int s = srcs[beg];
  float esv = es1[s * 4 + hd];
  float xv = xp1[(size_t)s * HC + lane];
  for (int e = beg; e < end; ) {
    int e2 = e + 1;
    float esv2 = 0.f, xv2 = 0.f;
    if (e2 < end) {
      int s2 = srcs[e2];
      esv2 = es1[s2 * 4 + hd];
      xv2 = xp1[(size_t)s2 * HC + lane];
    }
    float v = lrelu(esv + edh);
    float mn = fmaxf(m, v);
    float sc = __expf(m - mn);   // first iter: exp(-inf)=0
    float w = __expf(v - mn);
    z = z * sc + w;
    acc = acc * sc + w * xv;
    m = mn;
    e = e2; esv = esv2; xv = xv2;
  }
  h[(size_t)wid * HC + lane] = fmaxf(acc / (z + 1e-16f) + b1[lane], 0.f);
}

// ---------------- layer 2 projection: xp2 = h @ W2, es2/ed2 dots ----------------
__global__ __launch_bounds__(256) void layer2_kernel(
    const float* __restrict__ h, const float* __restrict__ W2,
    const float* __restrict__ a_s2, const float* __restrict__ a_d2,
    float* __restrict__ xp2, float* __restrict__ es2, float* __restrict__ ed2, int n) {
  __shared__ float W2l[64 * OUT_DIM];
  __shared__ float hl[4][64];
  int tid = threadIdx.x;
  for (int i = tid; i < 64 * OUT_DIM; i += 256) W2l[i] = W2[i];
  int r = tid >> 6, j = tid & 63;
  int row = blockIdx.x * 4 + r;
  if (row < n) hl[r][j] = h[(size_t)row * 64 + j];
  __syncthreads();
  if (row >= n) return;
  float ps = 0.f, pd = 0.f;
  if (j < OUT_DIM) {
    float sum = 0.f;
    #pragma unroll 8
    for (int k = 0; k < 64; ++k) sum += hl[r][k] * W2l[k * OUT_DIM + j];
    xp2[(size_t)row * OUT_DIM + j] = sum;
    ps = sum * a_s2[j];
    pd = sum * a_d2[j];
  }
  #pragma unroll
  for (int o = 32; o; o >>= 1) {
    ps += __shfl_down(ps, o, 64);
    pd += __shfl_down(pd, o, 64);
  }
  if (j == 0) { es2[row] = ps; ed2[row] = pd; }
}

// ---------------- layer 2 aggregation: one wave per dst node, writes d_out ----------------
__global__ __launch_bounds__(256) void agg2_csr(
    const int* __restrict__ offs, const int* __restrict__ srcs,
    const float* __restrict__ es2, const float* __restrict__ ed2,
    const float* __restrict__ xp2, const float* __restrict__ b2,
    float* __restrict__ out, int n) {
  int wid = (blockIdx.x * 256 + threadIdx.x) >> 6;
  if (wid >= n) return;
  int lane = threadIdx.x & 63;
  int beg = offs[wid], end = offs[wid + 1];
  float edv = ed2[wid];
  float m = -INFINITY, z = 0.f, acc = 0.f;
  int s = srcs[beg];
  float esv = es2[s];
  float xv = (lane < OUT_DIM) ? xp2[(size_t)s * OUT_DIM + lane] : 0.f;
  for (int e = beg; e < end; ) {
    int e2 = e + 1;
    float esv2 = 0.f, xv2 = 0.f;
    if (e2 < end) {
      int s2 = srcs[e2];
      esv2 = es2[s2];
      xv2 = (lane < OUT_DIM) ? xp2[(size_t)s2 * OUT_DIM + lane] : 0.f;
    }
    float v = lrelu(esv + edv);
    float mn = fmaxf(m, v);
    float sc = __expf(m - mn);
    float w = __expf(v - mn);
    z = z * sc + w;
    acc = acc * sc + w * xv;
    m = mn;
    e = e2; esv = esv2; xv = xv2;
  }
  if (lane < OUT_DIM)
    out[(size_t)wid * OUT_DIM + lane] = acc / (z + 1e-16f) + b2[lane];
}

extern "C" void kernel_launch(void* const* d_in, const int* in_sizes, int n_in,
                              void* d_out, int out_size, void* d_ws, size_t ws_size,
                              hipStream_t stream) {
  const float* x    = (const float*)d_in[0];
  const int*   ei   = (const int*)d_in[1];
  const float* W1   = (const float*)d_in[2];
  const float* a_s1 = (const float*)d_in[3];
  const float* a_d1 = (const float*)d_in[4];
  const float* b1   = (const float*)d_in[5];
  const float* W2   = (const float*)d_in[6];
  const float* a_s2 = (const float*)d_in[7];
  const float* a_d2 = (const float*)d_in[8];
  const float* b2   = (const float*)d_in[9];

  int n  = in_sizes[0] / IN_DIM;
  int E  = in_sizes[1] / 2;
  int ET = E + n;
  float* out = (float*)d_out;

  char* ws = (char*)d_ws;
  size_t off = 0;
  auto alloc = [&](size_t bytes) -> void* {
    void* p = ws + off;
    off = (off + bytes + 255) & ~(size_t)255;
    return p;
  };
  float*  xp1   = (float*)alloc((size_t)n * HC * 4);     // reused as xp2 later
  float*  h     = (float*)alloc((size_t)n * HC * 4);
  float*  es1   = (float*)alloc((size_t)n * 4 * 4);
  float*  ed1   = (float*)alloc((size_t)n * 4 * 4);
  float*  es2   = (float*)alloc((size_t)n * 4);
  float*  ed2   = (float*)alloc((size_t)n * 4);
  int*    deg   = (int*)alloc((size_t)n * 4);
  int*    cnt   = (int*)alloc((size_t)n * 4);
  int*    offs  = (int*)alloc((size_t)(n + 1) * 4);
  int*    part  = (int*)alloc((size_t)1024 * 4);
  int*    srcs  = (int*)alloc((size_t)ET * 4);
  __bf16* Wt_hi = (__bf16*)alloc((size_t)IN_DIM * HC * 2);
  __bf16* Wt_lo = (__bf16*)alloc((size_t)IN_DIM * HC * 2);
  float*  xp2   = xp1;  // xp1 dead after agg1_csr

  int nb = (n + 1023) / 1024;   // scan blocks

  zero_kernel<<<(n + 255) / 256, 256, 0, stream>>>(deg, cnt, n);
  count_kernel<<<(ET + 255) / 256, 256, 0, stream>>>(ei, deg, E, ET);
  scan1_kernel<<<nb, 256, 0, stream>>>(deg, offs, part, n);
  scan2_kernel<<<1, 256, 0, stream>>>(part, nb);
  scan3_kernel<<<(n + 255) / 256, 256, 0, stream>>>(offs, part, n, ET);
  scatter_kernel<<<(ET + 255) / 256, 256, 0, stream>>>(ei, offs, cnt, srcs, E, ET);

  wprep_kernel<<<(IN_DIM * HC + 255) / 256, 256, 0, stream>>>(W1, Wt_hi, Wt_lo);
  gemm1_mfma<<<(n + 63) / 64, 256, 0, stream>>>(x, Wt_hi, Wt_lo, a_s1, a_d1,
                                                xp1, es1, ed1, n);
  agg1_csr<<<(n * 64 + 255) / 256, 256, 0, stream>>>(offs, srcs, es1, ed1, xp1, b1, h, n);
  layer2_kernel<<<(n + 3) / 4, 256, 0, stream>>>(h, W2, a_s2, a_d2, xp2, es2, ed2, n);
  agg2_csr<<<(n * 64 + 255) / 256, 256, 0, stream>>>(offs, srcs, es2, ed2, xp2, b2, out, n);
}

// Round 4
// 466.114 us; speedup vs baseline: 3.1550x; 1.4515x over previous
//
#include <hip/hip_runtime.h>
#include <hip/hip_bf16.h>

#define IN_DIM 256
#define HC     64    // H*C for layer 1
#define OUT_DIM 40
#define NEG    0.2f

typedef __bf16 bf16x8 __attribute__((ext_vector_type(8)));
typedef float  f32x4  __attribute__((ext_vector_type(4)));

__device__ inline float lrelu(float v) { return fmaxf(v, NEG * v); }  // NEG<1

// ---------------- zero deg/cnt ----------------
__global__ void zero_kernel(int* __restrict__ deg, int* __restrict__ cnt, int n) {
  int i = blockIdx.x * blockDim.x + threadIdx.x;
  if (i < n) { deg[i] = 0; cnt[i] = 0; }
}

// ---------------- CSR build: histogram ----------------
__global__ void count_kernel(const int* __restrict__ ei, int* __restrict__ deg,
                             int E, int ET) {
  int e = blockIdx.x * blockDim.x + threadIdx.x;
  if (e >= ET) return;
  int d = (e < E) ? ei[E + e] : (e - E);   // self-loops appended
  atomicAdd(&deg[d], 1);
}

// ---------------- CSR build: 3-phase exclusive scan (1024 elems/block) ----------------
__global__ void scan1_kernel(const int* __restrict__ deg, int* __restrict__ offs,
                             int* __restrict__ partial, int n) {
  __shared__ int sm[256];
  int tid = threadIdx.x;
  int base = blockIdx.x * 1024 + tid * 4;
  int v0 = 0, v1 = 0, v2 = 0, v3 = 0;
  if (base + 0 < n) v0 = deg[base + 0];
  if (base + 1 < n) v1 = deg[base + 1];
  if (base + 2 < n) v2 = deg[base + 2];
  if (base + 3 < n) v3 = deg[base + 3];
  int t = v0 + v1 + v2 + v3;
  sm[tid] = t; __syncthreads();
  for (int o = 1; o < 256; o <<= 1) {
    int x = (tid >= o) ? sm[tid - o] : 0;
    __syncthreads();
    sm[tid] += x;
    __syncthreads();
  }
  int excl = sm[tid] - t;
  if (base + 0 < n) offs[base + 0] = excl;
  if (base + 1 < n) offs[base + 1] = excl + v0;
  if (base + 2 < n) offs[base + 2] = excl + v0 + v1;
  if (base + 3 < n) offs[base + 3] = excl + v0 + v1 + v2;
  if (tid == 255) partial[blockIdx.x] = sm[255];
}

__global__ void scan2_kernel(int* __restrict__ partial, int nb) {
  __shared__ int sm[256];
  int tid = threadIdx.x;
  int base = 0;
  for (int c = 0; c < nb; c += 256) {
    int idx = c + tid;
    int t = (idx < nb) ? partial[idx] : 0;
    sm[tid] = t; __syncthreads();
    for (int o = 1; o < 256; o <<= 1) {
      int x = (tid >= o) ? sm[tid - o] : 0;
      __syncthreads();
      sm[tid] += x;
      __syncthreads();
    }
    if (idx < nb) partial[idx] = base + sm[tid] - t;
    base += sm[255];
    __syncthreads();
  }
}

__global__ void scan3_kernel(int* __restrict__ offs, const int* __restrict__ partial,
                             int n, int ET) {
  int i = blockIdx.x * blockDim.x + threadIdx.x;
  if (i < n) offs[i] += partial[i >> 10];
  if (i == 0) offs[n] = ET;
}

// ---------------- CSR build: scatter src ids into dst-sorted order ----------------
__global__ void scatter_kernel(const int* __restrict__ ei, const int* __restrict__ offs,
                               int* __restrict__ cnt, int* __restrict__ srcs,
                               int E, int ET) {
  int e = blockIdx.x * blockDim.x + threadIdx.x;
  if (e >= ET) return;
  int s, d;
  if (e < E) { s = ei[e]; d = ei[E + e]; }
  else       { s = e - E; d = e - E; }
  int pos = offs[d] + atomicAdd(&cnt[d], 1);
  srcs[pos] = s;
}

// ---------------- W1 prep: transpose to [64][256] and split into bf16 hi/lo ----------------
__global__ void wprep_kernel(const float* __restrict__ W1,
                             __bf16* __restrict__ Wt_hi, __bf16* __restrict__ Wt_lo) {
  int i = blockIdx.x * blockDim.x + threadIdx.x;   // over 256*64
  if (i >= IN_DIM * HC) return;
  int k = i >> 6, nn = i & 63;
  float f = W1[i];
  __bf16 h = (__bf16)f;
  __bf16 l = (__bf16)(f - (float)h);
  Wt_hi[nn * IN_DIM + k] = h;
  Wt_lo[nn * IN_DIM + k] = l;
}

// ---------------- layer 1 projection via MFMA (split-bf16, 3 products) ----------------
__global__ __launch_bounds__(256) void gemm1_mfma(
    const float* __restrict__ x,
    const __bf16* __restrict__ Wt_hi, const __bf16* __restrict__ Wt_lo,
    const float* __restrict__ a_s, const float* __restrict__ a_d,
    float* __restrict__ xp1, float* __restrict__ es1, float* __restrict__ ed1, int n) {
  int wave = threadIdx.x >> 6, lane = threadIdx.x & 63;
  int l15 = lane & 15, kgrp = lane >> 4;
  int rowA = blockIdx.x * 64 + wave * 16 + l15;
  bool okA = rowA < n;
  const float* xrow = x + (size_t)rowA * IN_DIM;

  f32x4 acc[4] = {};
  #pragma unroll
  for (int c = 0; c < 8; ++c) {
    int k0 = c * 32 + kgrp * 8;
    f32x4 v0 = {}, v1 = {};
    if (okA) {
      v0 = *(const f32x4*)(xrow + k0);
      v1 = *(const f32x4*)(xrow + k0 + 4);
    }
    bf16x8 ahi, alo;
    #pragma unroll
    for (int i = 0; i < 4; ++i) {
      float f0 = v0[i], f1 = v1[i];
      __bf16 h0 = (__bf16)f0, h1 = (__bf16)f1;
      ahi[i]     = h0;
      ahi[4 + i] = h1;
      alo[i]     = (__bf16)(f0 - (float)h0);
      alo[4 + i] = (__bf16)(f1 - (float)h1);
    }
    #pragma unroll
    for (int t = 0; t < 4; ++t) {
      const __bf16* wph = Wt_hi + ((t * 16 + l15) * IN_DIM + k0);
      const __bf16* wpl = Wt_lo + ((t * 16 + l15) * IN_DIM + k0);
      bf16x8 bhi = *(const bf16x8*)wph;
      bf16x8 blo = *(const bf16x8*)wpl;
      acc[t] = __builtin_amdgcn_mfma_f32_16x16x32_bf16(ahi, bhi, acc[t], 0, 0, 0);
      acc[t] = __builtin_amdgcn_mfma_f32_16x16x32_bf16(ahi, blo, acc[t], 0, 0, 0);
      acc[t] = __builtin_amdgcn_mfma_f32_16x16x32_bf16(alo, bhi, acc[t], 0, 0, 0);
    }
  }

  // epilogue: write xp1 + fused es/ed attention dots (per-head = per 16-col tile)
  int rowbase = blockIdx.x * 64 + wave * 16 + kgrp * 4;
  #pragma unroll
  for (int t = 0; t < 4; ++t) {
    float as_v = a_s[t * 16 + l15], ad_v = a_d[t * 16 + l15];
    #pragma unroll
    for (int r = 0; r < 4; ++r) {
      int row = rowbase + r;
      float v = acc[t][r];
      bool ok = row < n;
      if (ok) xp1[(size_t)row * HC + t * 16 + l15] = v;
      float ps = v * as_v, pd = v * ad_v;
      #pragma unroll
      for (int o = 1; o < 16; o <<= 1) {
        ps += __shfl_xor(ps, o, 16);
        pd += __shfl_xor(pd, o, 16);
      }
      if (ok && l15 == 0) {
        es1[row * 4 + t] = ps;
        ed1[row * 4 + t] = pd;
      }
    }
  }
}

// ---------------- layer 1 aggregation: chunked two-phase softmax ----------------
// One wave per dst node. Phase A: lanes = (edge, head) pairs, 16 edges/chunk;
// per-chunk max + single online rescale; {ex, src_off} -> LDS.
// Phase B: lanes = channels; per edge: broadcast LDS read + 1 load + 1 fma.
__global__ __launch_bounds__(256) void agg1_csr(
    const int* __restrict__ offs, const int* __restrict__ srcs,
    const float* __restrict__ es1, const float* __restrict__ ed1,
    const float* __restrict__ xp1, const float* __restrict__ b1,
    float* __restrict__ hout, int n) {
  __shared__ float lds[4][16 * 4 * 2];
  int wave = threadIdx.x >> 6;
  int wid = (blockIdx.x * 256 + threadIdx.x) >> 6;
  if (wid >= n) return;
  int lane = threadIdx.x & 63;
  int eidx = lane >> 2, hA = lane & 3;   // phase-A view
  int hd = lane >> 4;                     // phase-B (channel) head
  int beg = offs[wid], end = offs[wid + 1];
  float edh = ed1[wid * 4 + hA];
  float m = -INFINITY, zacc = 0.f, acc = 0.f;
  const char* xcol = (const char*)(xp1 + lane);
  float* myl = lds[wave];

  for (int e0 = beg; e0 < end; e0 += 16) {
    int cnt = min(16, end - e0);
    // ---- phase A (edge view) ----
    float v = -INFINITY;
    int s = 0;
    if (eidx < cnt) {
      s = srcs[e0 + eidx];
      v = lrelu(es1[s * 4 + hA] + edh);
    }
    float mc = v;
    mc = fmaxf(mc, __shfl_xor(mc, 4));
    mc = fmaxf(mc, __shfl_xor(mc, 8));
    mc = fmaxf(mc, __shfl_xor(mc, 16));
    mc = fmaxf(mc, __shfl_xor(mc, 32));
    float mnew = fmaxf(m, mc);
    float sc = __expf(m - mnew);          // first chunk: exp(-inf)=0
    float ex = (eidx < cnt) ? __expf(v - mnew) : 0.f;
    zacc = zacc * sc + ex;
    m = mnew;
    myl[lane * 2]     = ex;
    myl[lane * 2 + 1] = __int_as_float(s * (int)(HC * sizeof(float)));
    // ---- rescale acc (channel view) ----
    float sc_c = __shfl(sc, hd);          // lane hd holds head hd's sc
    acc *= sc_c;
    // ---- phase B (channel view) ----
    #pragma unroll 4
    for (int j = 0; j < cnt; ++j) {
      float2 ao = *(const float2*)&myl[(j * 4 + hd) * 2];
      float xv = *(const float*)(xcol + __float_as_int(ao.y));
      acc = fmaf(ao.x, xv, acc);
    }
  }

  float z = zacc;
  z += __shfl_xor(z, 4); z += __shfl_xor(z, 8);
  z += __shfl_xor(z, 16); z += __shfl_xor(z, 32);
  float zc = __shfl(z, hd);
  hout[(size_t)wid * HC + lane] = fmaxf(acc / (zc + 1e-16f) + b1[lane], 0.f);
}

// ---------------- layer 2 projection: xp2 = h @ W2, es2/ed2 dots ----------------
__global__ __launch_bounds__(256) void layer2_kernel(
    const float* __restrict__ h, const float* __restrict__ W2,
    const float* __restrict__ a_s2, const float* __restrict__ a_d2,
    float* __restrict__ xp2, float* __restrict__ es2, float* __restrict__ ed2, int n) {
  __shared__ float W2l[64 * OUT_DIM];
  __shared__ float hl[4][64];
  int tid = threadIdx.x;
  for (int i = tid; i < 64 * OUT_DIM; i += 256) W2l[i] = W2[i];
  int r = tid >> 6, j = tid & 63;
  int row = blockIdx.x * 4 + r;
  if (row < n) hl[r][j] = h[(size_t)row * 64 + j];
  __syncthreads();
  if (row >= n) return;
  float ps = 0.f, pd = 0.f;
  if (j < OUT_DIM) {
    float sum = 0.f;
    #pragma unroll 8
    for (int k = 0; k < 64; ++k) sum += hl[r][k] * W2l[k * OUT_DIM + j];
    xp2[(size_t)row * OUT_DIM + j] = sum;
    ps = sum * a_s2[j];
    pd = sum * a_d2[j];
  }
  #pragma unroll
  for (int o = 32; o; o >>= 1) {
    ps += __shfl_down(ps, o, 64);
    pd += __shfl_down(pd, o, 64);
  }
  if (j == 0) { es2[row] = ps; ed2[row] = pd; }
}

// ---------------- layer 2 aggregation: chunked two-phase softmax ----------------
__global__ __launch_bounds__(256) void agg2_csr(
    const int* __restrict__ offs, const int* __restrict__ srcs,
    const float* __restrict__ es2, const float* __restrict__ ed2,
    const float* __restrict__ xp2, const float* __restrict__ b2,
    float* __restrict__ out, int n) {
  __shared__ float lds[4][64 * 2];
  int wave = threadIdx.x >> 6;
  int wid = (blockIdx.x * 256 + threadIdx.x) >> 6;
  if (wid >= n) return;
  int lane = threadIdx.x & 63;
  int beg = offs[wid], end = offs[wid + 1];
  float edv = ed2[wid];
  float m = -INFINITY, zacc = 0.f, acc = 0.f;
  const char* xcol = (const char*)(xp2 + lane);
  float* myl = lds[wave];

  for (int e0 = beg; e0 < end; e0 += 64) {
    int cnt = min(64, end - e0);
    // ---- phase A: lanes = edges ----
    float v = -INFINITY;
    int s = 0;
    if (lane < cnt) {
      s = srcs[e0 + lane];
      v = lrelu(es2[s] + edv);
    }
    float mc = v;
    #pragma unroll
    for (int o = 1; o < 64; o <<= 1) mc = fmaxf(mc, __shfl_xor(mc, o));
    float mnew = fmaxf(m, mc);
    float sc = __expf(m - mnew);
    float ex = (lane < cnt) ? __expf(v - mnew) : 0.f;
    zacc = zacc * sc + ex;
    m = mnew;
    myl[lane * 2]     = ex;
    myl[lane * 2 + 1] = __int_as_float(s * (int)(OUT_DIM * sizeof(float)));
    acc *= sc;                              // single head: sc uniform
    // ---- phase B: lanes = channels (40 active) ----
    if (lane < OUT_DIM) {
      #pragma unroll 4
      for (int j = 0; j < cnt; ++j) {
        float2 ao = *(const float2*)&myl[j * 2];   // uniform addr -> broadcast
        float xv = *(const float*)(xcol + __float_as_int(ao.y));
        acc = fmaf(ao.x, xv, acc);
      }
    }
  }

  float z = zacc;
  #pragma unroll
  for (int o = 1; o < 64; o <<= 1) z += __shfl_xor(z, o);
  if (lane < OUT_DIM)
    out[(size_t)wid * OUT_DIM + lane] = acc / (z + 1e-16f) + b2[lane];
}

extern "C" void kernel_launch(void* const* d_in, const int* in_sizes, int n_in,
                              void* d_out, int out_size, void* d_ws, size_t ws_size,
                              hipStream_t stream) {
  const float* x    = (const float*)d_in[0];
  const int*   ei   = (const int*)d_in[1];
  const float* W1   = (const float*)d_in[2];
  const float* a_s1 = (const float*)d_in[3];
  const float* a_d1 = (const float*)d_in[4];
  const float* b1   = (const float*)d_in[5];
  const float* W2   = (const float*)d_in[6];
  const float* a_s2 = (const float*)d_in[7];
  const float* a_d2 = (const float*)d_in[8];
  const float* b2   = (const float*)d_in[9];

  int n  = in_sizes[0] / IN_DIM;
  int E  = in_sizes[1] / 2;
  int ET = E + n;
  float* out = (float*)d_out;

  char* ws = (char*)d_ws;
  size_t off = 0;
  auto alloc = [&](size_t bytes) -> void* {
    void* p = ws + off;
    off = (off + bytes + 255) & ~(size_t)255;
    return p;
  };
  float*  xp1   = (float*)alloc((size_t)n * HC * 4);     // reused as xp2 later
  float*  h     = (float*)alloc((size_t)n * HC * 4);
  float*  es1   = (float*)alloc((size_t)n * 4 * 4);
  float*  ed1   = (float*)alloc((size_t)n * 4 * 4);
  float*  es2   = (float*)alloc((size_t)n * 4);
  float*  ed2   = (float*)alloc((size_t)n * 4);
  int*    deg   = (int*)alloc((size_t)n * 4);
  int*    cnt   = (int*)alloc((size_t)n * 4);
  int*    offs  = (int*)alloc((size_t)(n + 1) * 4);
  int*    part  = (int*)alloc((size_t)1024 * 4);
  int*    srcs  = (int*)alloc((size_t)ET * 4);
  __bf16* Wt_hi = (__bf16*)alloc((size_t)IN_DIM * HC * 2);
  __bf16* Wt_lo = (__bf16*)alloc((size_t)IN_DIM * HC * 2);
  float*  xp2   = xp1;  // xp1 dead after agg1_csr

  int nb = (n + 1023) / 1024;   // scan blocks

  zero_kernel<<<(n + 255) / 256, 256, 0, stream>>>(deg, cnt, n);
  count_kernel<<<(ET + 255) / 256, 256, 0, stream>>>(ei, deg, E, ET);
  scan1_kernel<<<nb, 256, 0, stream>>>(deg, offs, part, n);
  scan2_kernel<<<1, 256, 0, stream>>>(part, nb);
  scan3_kernel<<<(n + 255) / 256, 256, 0, stream>>>(offs, part, n, ET);
  scatter_kernel<<<(ET + 255) / 256, 256, 0, stream>>>(ei, offs, cnt, srcs, E, ET);

  wprep_kernel<<<(IN_DIM * HC + 255) / 256, 256, 0, stream>>>(W1, Wt_hi, Wt_lo);
  gemm1_mfma<<<(n + 63) / 64, 256, 0, stream>>>(x, Wt_hi, Wt_lo, a_s1, a_d1,
                                                xp1, es1, ed1, n);
  agg1_csr<<<(n * 64 + 255) / 256, 256, 0, stream>>>(offs, srcs, es1, ed1, xp1, b1, h, n);
  layer2_kernel<<<(n + 3) / 4, 256, 0, stream>>>(h, W2, a_s2, a_d2, xp2, es2, ed2, n);
  agg2_csr<<<(n * 64 + 255) / 256, 256, 0, stream>>>(offs, srcs, es2, ed2, xp2, b2, out, n);
}

// Round 5
// 464.256 us; speedup vs baseline: 3.1677x; 1.0040x over previous
//
#include <hip/hip_runtime.h>
#include <hip/hip_bf16.h>

#define IN_DIM 256
#define HC     64    // H*C for layer 1
#define OUT_DIM 40
#define NEG    0.2f

#define NPB    16    // nodes per bucket (power of 2)
#define NPB_SH 4
#define S2_CAP 2048  // staged entries per bucket (mean ~280 for deg~17)

typedef __bf16 bf16x8 __attribute__((ext_vector_type(8)));
typedef float  f32x4  __attribute__((ext_vector_type(4)));

__device__ inline float lrelu(float v) { return fmaxf(v, NEG * v); }  // NEG<1

// ---------------- zero deg/bcnt ----------------
__global__ void zero_kernel(int* __restrict__ deg, int* __restrict__ bcnt,
                            int n, int nbuck) {
  int i = blockIdx.x * blockDim.x + threadIdx.x;
  if (i < n) deg[i] = 0;
  if (i < nbuck) bcnt[i] = 0;
}

// ---------------- CSR build: histogram ----------------
__global__ void count_kernel(const int* __restrict__ ei, int* __restrict__ deg,
                             int E, int ET) {
  int e = blockIdx.x * blockDim.x + threadIdx.x;
  if (e >= ET) return;
  int d = (e < E) ? ei[E + e] : (e - E);   // self-loops appended
  atomicAdd(&deg[d], 1);
}

// ---------------- CSR build: 3-phase exclusive scan (1024 elems/block) ----------------
__global__ void scan1_kernel(const int* __restrict__ deg, int* __restrict__ offs,
                             int* __restrict__ partial, int n) {
  __shared__ int sm[256];
  int tid = threadIdx.x;
  int base = blockIdx.x * 1024 + tid * 4;
  int v0 = 0, v1 = 0, v2 = 0, v3 = 0;
  if (base + 0 < n) v0 = deg[base + 0];
  if (base + 1 < n) v1 = deg[base + 1];
  if (base + 2 < n) v2 = deg[base + 2];
  if (base + 3 < n) v3 = deg[base + 3];
  int t = v0 + v1 + v2 + v3;
  sm[tid] = t; __syncthreads();
  for (int o = 1; o < 256; o <<= 1) {
    int x = (tid >= o) ? sm[tid - o] : 0;
    __syncthreads();
    sm[tid] += x;
    __syncthreads();
  }
  int excl = sm[tid] - t;
  if (base + 0 < n) offs[base + 0] = excl;
  if (base + 1 < n) offs[base + 1] = excl + v0;
  if (base + 2 < n) offs[base + 2] = excl + v0 + v1;
  if (base + 3 < n) offs[base + 3] = excl + v0 + v1 + v2;
  if (tid == 255) partial[blockIdx.x] = sm[255];
}

__global__ void scan2_kernel(int* __restrict__ partial, int nb) {
  __shared__ int sm[256];
  int tid = threadIdx.x;
  int base = 0;
  for (int c = 0; c < nb; c += 256) {
    int idx = c + tid;
    int t = (idx < nb) ? partial[idx] : 0;
    sm[tid] = t; __syncthreads();
    for (int o = 1; o < 256; o <<= 1) {
      int x = (tid >= o) ? sm[tid - o] : 0;
      __syncthreads();
      sm[tid] += x;
      __syncthreads();
    }
    if (idx < nb) partial[idx] = base + sm[tid] - t;
    base += sm[255];
    __syncthreads();
  }
}

__global__ void scan3_kernel(int* __restrict__ offs, const int* __restrict__ partial,
                             int n, int ET) {
  int i = blockIdx.x * blockDim.x + threadIdx.x;
  if (i < n) offs[i] += partial[i >> 10];
  if (i == 0) offs[n] = ET;
}

// ---------------- sort pass 1: bin edges into node-range buckets ----------------
// bucket b = d >> NPB_SH covers nodes [b*NPB, (b+1)*NPB); its srcs region starts
// at offs[b*NPB]. Payload packs src (27b) | dlocal (5b).
__global__ void bucket_scatter(const int* __restrict__ ei, const int* __restrict__ offs,
                               int* __restrict__ bcnt, unsigned int* __restrict__ pairs,
                               int E, int ET) {
  int e = blockIdx.x * blockDim.x + threadIdx.x;
  if (e >= ET) return;
  int s, d;
  if (e < E) { s = ei[e]; d = ei[E + e]; }
  else       { s = e - E; d = e - E; }
  int b = d >> NPB_SH;
  int pos = offs[b << NPB_SH] + atomicAdd(&bcnt[b], 1);
  pairs[pos] = (unsigned)s | ((unsigned)(d & (NPB - 1)) << 27);
}

// ---------------- sort pass 2: rank within bucket via LDS, coalesced write ----------------
__global__ __launch_bounds__(256) void place_kernel(
    const unsigned int* __restrict__ pairs, const int* __restrict__ offs,
    int* __restrict__ srcs, int n) {
  __shared__ int loc[S2_CAP];
  __shared__ int lcnt[NPB];
  __shared__ int lofs[NPB + 1];
  int b = blockIdx.x;
  int node0 = b << NPB_SH;
  if (node0 >= n) return;
  int tid = threadIdx.x;
  int nloc = min(NPB, n - node0);
  if (tid < NPB) lcnt[tid] = 0;
  if (tid <= nloc) lofs[tid] = offs[node0 + tid];
  __syncthreads();
  int rbeg = lofs[0], rend = lofs[nloc];
  int len = rend - rbeg;
  if (len <= S2_CAP) {
    for (int i = tid; i < len; i += 256) {
      unsigned p = pairs[rbeg + i];
      int s = (int)(p & ((1u << 27) - 1));
      int dl = (int)(p >> 27);
      int r = atomicAdd(&lcnt[dl], 1);
      loc[lofs[dl] - rbeg + r] = s;
    }
    __syncthreads();
    for (int i = tid; i < len; i += 256) srcs[rbeg + i] = loc[i];
  } else {
    for (int i = tid; i < len; i += 256) {
      unsigned p = pairs[rbeg + i];
      int s = (int)(p & ((1u << 27) - 1));
      int dl = (int)(p >> 27);
      int r = atomicAdd(&lcnt[dl], 1);
      srcs[lofs[dl] + r] = s;
    }
  }
}

// ---------------- W1 prep: transpose to [64][256] and split into bf16 hi/lo ----------------
__global__ void wprep_kernel(const float* __restrict__ W1,
                             __bf16* __restrict__ Wt_hi, __bf16* __restrict__ Wt_lo) {
  int i = blockIdx.x * blockDim.x + threadIdx.x;   // over 256*64
  if (i >= IN_DIM * HC) return;
  int k = i >> 6, nn = i & 63;
  float f = W1[i];
  __bf16 h = (__bf16)f;
  __bf16 l = (__bf16)(f - (float)h);
  Wt_hi[nn * IN_DIM + k] = h;
  Wt_lo[nn * IN_DIM + k] = l;
}

// ---------------- layer 1 projection via MFMA (split-bf16, 3 products) ----------------
__global__ __launch_bounds__(256) void gemm1_mfma(
    const float* __restrict__ x,
    const __bf16* __restrict__ Wt_hi, const __bf16* __restrict__ Wt_lo,
    const float* __restrict__ a_s, const float* __restrict__ a_d,
    float* __restrict__ xp1, float* __restrict__ es1, float* __restrict__ ed1, int n) {
  int wave = threadIdx.x >> 6, lane = threadIdx.x & 63;
  int l15 = lane & 15, kgrp = lane >> 4;
  int rowA = blockIdx.x * 64 + wave * 16 + l15;
  bool okA = rowA < n;
  const float* xrow = x + (size_t)rowA * IN_DIM;

  f32x4 acc[4] = {};
  #pragma unroll
  for (int c = 0; c < 8; ++c) {
    int k0 = c * 32 + kgrp * 8;
    f32x4 v0 = {}, v1 = {};
    if (okA) {
      v0 = *(const f32x4*)(xrow + k0);
      v1 = *(const f32x4*)(xrow + k0 + 4);
    }
    bf16x8 ahi, alo;
    #pragma unroll
    for (int i = 0; i < 4; ++i) {
      float f0 = v0[i], f1 = v1[i];
      __bf16 h0 = (__bf16)f0, h1 = (__bf16)f1;
      ahi[i]     = h0;
      ahi[4 + i] = h1;
      alo[i]     = (__bf16)(f0 - (float)h0);
      alo[4 + i] = (__bf16)(f1 - (float)h1);
    }
    #pragma unroll
    for (int t = 0; t < 4; ++t) {
      const __bf16* wph = Wt_hi + ((t * 16 + l15) * IN_DIM + k0);
      const __bf16* wpl = Wt_lo + ((t * 16 + l15) * IN_DIM + k0);
      bf16x8 bhi = *(const bf16x8*)wph;
      bf16x8 blo = *(const bf16x8*)wpl;
      acc[t] = __builtin_amdgcn_mfma_f32_16x16x32_bf16(ahi, bhi, acc[t], 0, 0, 0);
      acc[t] = __builtin_amdgcn_mfma_f32_16x16x32_bf16(ahi, blo, acc[t], 0, 0, 0);
      acc[t] = __builtin_amdgcn_mfma_f32_16x16x32_bf16(alo, bhi, acc[t], 0, 0, 0);
    }
  }

  // epilogue: write xp1 + fused es/ed attention dots (per-head = per 16-col tile)
  int rowbase = blockIdx.x * 64 + wave * 16 + kgrp * 4;
  #pragma unroll
  for (int t = 0; t < 4; ++t) {
    float as_v = a_s[t * 16 + l15], ad_v = a_d[t * 16 + l15];
    #pragma unroll
    for (int r = 0; r < 4; ++r) {
      int row = rowbase + r;
      float v = acc[t][r];
      bool ok = row < n;
      if (ok) xp1[(size_t)row * HC + t * 16 + l15] = v;
      float ps = v * as_v, pd = v * ad_v;
      #pragma unroll
      for (int o = 1; o < 16; o <<= 1) {
        ps += __shfl_xor(ps, o, 16);
        pd += __shfl_xor(pd, o, 16);
      }
      if (ok && l15 == 0) {
        es1[row * 4 + t] = ps;
        ed1[row * 4 + t] = pd;
      }
    }
  }
}

// ---------------- layer 1 aggregation: chunked two-phase softmax ----------------
__global__ __launch_bounds__(256) void agg1_csr(
    const int* __restrict__ offs, const int* __restrict__ srcs,
    const float* __restrict__ es1, const float* __restrict__ ed1,
    const float* __restrict__ xp1, const float* __restrict__ b1,
    float* __restrict__ hout, int n) {
  __shared__ float lds[4][16 * 4 * 2];
  int wave = threadIdx.x >> 6;
  int wid = (blockIdx.x * 256 + threadIdx.x) >> 6;
  if (wid >= n) return;
  int lane = threadIdx.x & 63;
  int eidx = lane >> 2, hA = lane & 3;   // phase-A view
  int hd = lane >> 4;                     // phase-B (channel) head
  int beg = offs[wid], end = offs[wid + 1];
  float edh = ed1[wid * 4 + hA];
  float m = -INFINITY, zacc = 0.f, acc = 0.f;
  const char* xcol = (const char*)(xp1 + lane);
  float* myl = lds[wave];

  for (int e0 = beg; e0 < end; e0 += 16) {
    int cnt = min(16, end - e0);
    // ---- phase A (edge view) ----
    float v = -INFINITY;
    int s = 0;
    if (eidx < cnt) {
      s = srcs[e0 + eidx];
      v = lrelu(es1[s * 4 + hA] + edh);
    }
    float mc = v;
    mc = fmaxf(mc, __shfl_xor(mc, 4));
    mc = fmaxf(mc, __shfl_xor(mc, 8));
    mc = fmaxf(mc, __shfl_xor(mc, 16));
    mc = fmaxf(mc, __shfl_xor(mc, 32));
    float mnew = fmaxf(m, mc);
    float sc = __expf(m - mnew);          // first chunk: exp(-inf)=0
    float ex = (eidx < cnt) ? __expf(v - mnew) : 0.f;
    zacc = zacc * sc + ex;
    m = mnew;
    myl[lane * 2]     = ex;
    myl[lane * 2 + 1] = __int_as_float(s * (int)(HC * sizeof(float)));
    // ---- rescale acc (channel view) ----
    float sc_c = __shfl(sc, hd);          // lane hd holds head hd's sc
    acc *= sc_c;
    // ---- phase B (channel view) ----
    #pragma unroll 4
    for (int j = 0; j < cnt; ++j) {
      float2 ao = *(const float2*)&myl[(j * 4 + hd) * 2];
      float xv = *(const float*)(xcol + __float_as_int(ao.y));
      acc = fmaf(ao.x, xv, acc);
    }
  }

  float z = zacc;
  z += __shfl_xor(z, 4); z += __shfl_xor(z, 8);
  z += __shfl_xor(z, 16); z += __shfl_xor(z, 32);
  float zc = __shfl(z, hd);
  hout[(size_t)wid * HC + lane] = fmaxf(acc / (zc + 1e-16f) + b1[lane], 0.f);
}

// ---------------- layer 2 projection: xp2 = h @ W2, es2/ed2 dots ----------------
__global__ __launch_bounds__(256) void layer2_kernel(
    const float* __restrict__ h, const float* __restrict__ W2,
    const float* __restrict__ a_s2, const float* __restrict__ a_d2,
    float* __restrict__ xp2, float* __restrict__ es2, float* __restrict__ ed2, int n) {
  __shared__ float W2l[64 * OUT_DIM];
  __shared__ float hl[4][64];
  int tid = threadIdx.x;
  for (int i = tid; i < 64 * OUT_DIM; i += 256) W2l[i] = W2[i];
  int r = tid >> 6, j = tid & 63;
  int row = blockIdx.x * 4 + r;
  if (row < n) hl[r][j] = h[(size_t)row * 64 + j];
  __syncthreads();
  if (row >= n) return;
  float ps = 0.f, pd = 0.f;
  if (j < OUT_DIM) {
    float sum = 0.f;
    #pragma unroll 8
    for (int k = 0; k < 64; ++k) sum += hl[r][k] * W2l[k * OUT_DIM + j];
    xp2[(size_t)row * OUT_DIM + j] = sum;
    ps = sum * a_s2[j];
    pd = sum * a_d2[j];
  }
  #pragma unroll
  for (int o = 32; o; o >>= 1) {
    ps += __shfl_down(ps, o, 64);
    pd += __shfl_down(pd, o, 64);
  }
  if (j == 0) { es2[row] = ps; ed2[row] = pd; }
}

// ---------------- layer 2 aggregation: chunked two-phase softmax ----------------
__global__ __launch_bounds__(256) void agg2_csr(
    const int* __restrict__ offs, const int* __restrict__ srcs,
    const float* __restrict__ es2, const float* __restrict__ ed2,
    const float* __restrict__ xp2, const float* __restrict__ b2,
    float* __restrict__ out, int n) {
  __shared__ float lds[4][64 * 2];
  int wave = threadIdx.x >> 6;
  int wid = (blockIdx.x * 256 + threadIdx.x) >> 6;
  if (wid >= n) return;
  int lane = threadIdx.x & 63;
  int beg = offs[wid], end = offs[wid + 1];
  float edv = ed2[wid];
  float m = -INFINITY, zacc = 0.f, acc = 0.f;
  const char* xcol = (const char*)(xp2 + lane);
  float* myl = lds[wave];

  for (int e0 = beg; e0 < end; e0 += 64) {
    int cnt = min(64, end - e0);
    // ---- phase A: lanes = edges ----
    float v = -INFINITY;
    int s = 0;
    if (lane < cnt) {
      s = srcs[e0 + lane];
      v = lrelu(es2[s] + edv);
    }
    float mc = v;
    #pragma unroll
    for (int o = 1; o < 64; o <<= 1) mc = fmaxf(mc, __shfl_xor(mc, o));
    float mnew = fmaxf(m, mc);
    float sc = __expf(m - mnew);
    float ex = (lane < cnt) ? __expf(v - mnew) : 0.f;
    zacc = zacc * sc + ex;
    m = mnew;
    myl[lane * 2]     = ex;
    myl[lane * 2 + 1] = __int_as_float(s * (int)(OUT_DIM * sizeof(float)));
    acc *= sc;                              // single head: sc uniform
    // ---- phase B: lanes = channels (40 active) ----
    if (lane < OUT_DIM) {
      #pragma unroll 4
      for (int j = 0; j < cnt; ++j) {
        float2 ao = *(const float2*)&myl[j * 2];   // uniform addr -> broadcast
        float xv = *(const float*)(xcol + __float_as_int(ao.y));
        acc = fmaf(ao.x, xv, acc);
      }
    }
  }

  float z = zacc;
  #pragma unroll
  for (int o = 1; o < 64; o <<= 1) z += __shfl_xor(z, o);
  if (lane < OUT_DIM)
    out[(size_t)wid * OUT_DIM + lane] = acc / (z + 1e-16f) + b2[lane];
}

extern "C" void kernel_launch(void* const* d_in, const int* in_sizes, int n_in,
                              void* d_out, int out_size, void* d_ws, size_t ws_size,
                              hipStream_t stream) {
  const float* x    = (const float*)d_in[0];
  const int*   ei   = (const int*)d_in[1];
  const float* W1   = (const float*)d_in[2];
  const float* a_s1 = (const float*)d_in[3];
  const float* a_d1 = (const float*)d_in[4];
  const float* b1   = (const float*)d_in[5];
  const float* W2   = (const float*)d_in[6];
  const float* a_s2 = (const float*)d_in[7];
  const float* a_d2 = (const float*)d_in[8];
  const float* b2   = (const float*)d_in[9];

  int n  = in_sizes[0] / IN_DIM;
  int E  = in_sizes[1] / 2;
  int ET = E + n;
  int nbuck = (n + NPB - 1) / NPB;
  float* out = (float*)d_out;

  char* ws = (char*)d_ws;
  size_t off = 0;
  auto alloc = [&](size_t bytes) -> void* {
    void* p = ws + off;
    off = (off + bytes + 255) & ~(size_t)255;
    return p;
  };
  float*  xp1   = (float*)alloc((size_t)n * HC * 4);     // reused as xp2 later
  float*  h     = (float*)alloc((size_t)n * HC * 4);
  float*  es1   = (float*)alloc((size_t)n * 4 * 4);
  float*  ed1   = (float*)alloc((size_t)n * 4 * 4);
  float*  es2   = (float*)alloc((size_t)n * 4);
  float*  ed2   = (float*)alloc((size_t)n * 4);
  int*    deg   = (int*)alloc((size_t)n * 4);
  int*    bcnt  = (int*)alloc((size_t)nbuck * 4);
  int*    offs  = (int*)alloc((size_t)(n + 1) * 4);
  int*    part  = (int*)alloc((size_t)1024 * 4);
  int*    srcs  = (int*)alloc((size_t)ET * 4);
  unsigned int* pairs = (unsigned int*)alloc((size_t)ET * 4);
  __bf16* Wt_hi = (__bf16*)alloc((size_t)IN_DIM * HC * 2);
  __bf16* Wt_lo = (__bf16*)alloc((size_t)IN_DIM * HC * 2);
  float*  xp2   = xp1;  // xp1 dead after agg1_csr

  int nb = (n + 1023) / 1024;   // scan blocks

  zero_kernel<<<(n + 255) / 256, 256, 0, stream>>>(deg, bcnt, n, nbuck);
  count_kernel<<<(ET + 255) / 256, 256, 0, stream>>>(ei, deg, E, ET);
  scan1_kernel<<<nb, 256, 0, stream>>>(deg, offs, part, n);
  scan2_kernel<<<1, 256, 0, stream>>>(part, nb);
  scan3_kernel<<<(n + 255) / 256, 256, 0, stream>>>(offs, part, n, ET);
  bucket_scatter<<<(ET + 255) / 256, 256, 0, stream>>>(ei, offs, bcnt, pairs, E, ET);
  place_kernel<<<nbuck, 256, 0, stream>>>(pairs, offs, srcs, n);

  wprep_kernel<<<(IN_DIM * HC + 255) / 256, 256, 0, stream>>>(W1, Wt_hi, Wt_lo);
  gemm1_mfma<<<(n + 63) / 64, 256, 0, stream>>>(x, Wt_hi, Wt_lo, a_s1, a_d1,
                                                xp1, es1, ed1, n);
  agg1_csr<<<(n * 64 + 255) / 256, 256, 0, stream>>>(offs, srcs, es1, ed1, xp1, b1, h, n);
  layer2_kernel<<<(n + 3) / 4, 256, 0, stream>>>(h, W2, a_s2, a_d2, xp2, es2, ed2, n);
  agg2_csr<<<(n * 64 + 255) / 256, 256, 0, stream>>>(offs, srcs, es2, ed2, xp2, b2, out, n);
}